// Round 1
// baseline (8329.929 us; speedup 1.0000x reference)
//
#include <hip/hip_runtime.h>
#include <math.h>

// Problem constants (fixed by setup_inputs)
#define BATCH 512
#define TSEQ  256
#define HID   512
#define G4    2048   // 4*H
#define DECSTEPS 42  // task_level

// Encoder GEMM tile: 64 batch x 64 cols (4 gates x 16 d)
#define BT 64
#define DT 16
#define KC 32
#define LP 36   // LDS row pitch in floats (32 + 4 pad, keeps 16B alignment)

__device__ __forceinline__ float sigf(float x) { return 1.0f / (1.0f + expf(-x)); }

// mode 0: one LSTM encoder step: gates = hin@Whh^T + x[:,t]*Wih + b; update c, write hout
// mode 1: dec_base = hin@Whh^T + b   (no x term; raw pre-activation gates)
__global__ __launch_bounds__(256) void lstm_gemm(
    const float* __restrict__ hin,    // [B,H]
    const float* __restrict__ Whh,    // [4H,H] row-major
    const float* __restrict__ Wih,    // [4H]
    const float* __restrict__ bih,
    const float* __restrict__ bhh,
    const float* __restrict__ x,      // [B,T]
    int t, int mode,
    float* __restrict__ hout,         // [B,H]  (mode 0)
    float* __restrict__ c,            // [B,H]  in/out (mode 0)
    float* __restrict__ dbase)        // [B,4H] (mode 1)
{
    const int tid   = threadIdx.x;
    const int bbase = blockIdx.x * BT;   // batch tile
    const int d0    = blockIdx.y * DT;   // d tile
    const int tx    = tid & 15;          // d within tile
    const int ty    = tid >> 4;          // batch group (4 rows)

    __shared__ float hs[BT * LP];
    __shared__ float wsl[64 * LP];

    float acc[4][4];
#pragma unroll
    for (int r = 0; r < 4; ++r)
#pragma unroll
        for (int g = 0; g < 4; ++g) acc[r][g] = 0.0f;

    // loader mapping: each thread loads two float4s per tile
    const int lr0 = tid >> 3;          // 0..31
    const int lr1 = lr0 + 32;          // 32..63
    const int lk  = (tid & 7) * 4;     // 0,4,...,28
    // W row index for LDS row cc: j = (cc>>4)*512 + d0 + (cc&15)
    const int j0 = ((lr0 >> 4) * HID) + d0 + (lr0 & 15);
    const int j1 = ((lr1 >> 4) * HID) + d0 + (lr1 & 15);
    const int b0g = bbase + lr0;
    const int b1g = bbase + lr1;

    for (int k0 = 0; k0 < HID; k0 += KC) {
        __syncthreads();
        *(float4*)&hs[lr0 * LP + lk]  = *(const float4*)&hin[b0g * HID + k0 + lk];
        *(float4*)&hs[lr1 * LP + lk]  = *(const float4*)&hin[b1g * HID + k0 + lk];
        *(float4*)&wsl[lr0 * LP + lk] = *(const float4*)&Whh[j0 * HID + k0 + lk];
        *(float4*)&wsl[lr1 * LP + lk] = *(const float4*)&Whh[j1 * HID + k0 + lk];
        __syncthreads();
#pragma unroll
        for (int kk = 0; kk < KC; kk += 4) {
            float4 a0 = *(float4*)&hs[(ty * 4 + 0) * LP + kk];
            float4 a1 = *(float4*)&hs[(ty * 4 + 1) * LP + kk];
            float4 a2 = *(float4*)&hs[(ty * 4 + 2) * LP + kk];
            float4 a3 = *(float4*)&hs[(ty * 4 + 3) * LP + kk];
            float4 w0 = *(float4*)&wsl[(tx +  0) * LP + kk];
            float4 w1 = *(float4*)&wsl[(tx + 16) * LP + kk];
            float4 w2 = *(float4*)&wsl[(tx + 32) * LP + kk];
            float4 w3 = *(float4*)&wsl[(tx + 48) * LP + kk];
#define DOT4(A, W, ACC) \
            ACC = __builtin_fmaf(A.x, W.x, ACC); \
            ACC = __builtin_fmaf(A.y, W.y, ACC); \
            ACC = __builtin_fmaf(A.z, W.z, ACC); \
            ACC = __builtin_fmaf(A.w, W.w, ACC);
            DOT4(a0, w0, acc[0][0]) DOT4(a0, w1, acc[0][1]) DOT4(a0, w2, acc[0][2]) DOT4(a0, w3, acc[0][3])
            DOT4(a1, w0, acc[1][0]) DOT4(a1, w1, acc[1][1]) DOT4(a1, w2, acc[1][2]) DOT4(a1, w3, acc[1][3])
            DOT4(a2, w0, acc[2][0]) DOT4(a2, w1, acc[2][1]) DOT4(a2, w2, acc[2][2]) DOT4(a2, w3, acc[2][3])
            DOT4(a3, w0, acc[3][0]) DOT4(a3, w1, acc[3][1]) DOT4(a3, w2, acc[3][2]) DOT4(a3, w3, acc[3][3])
#undef DOT4
        }
    }

    const int d = d0 + tx;
    const float bi0 = bih[d]          + bhh[d];
    const float bi1 = bih[HID + d]    + bhh[HID + d];
    const float bi2 = bih[2*HID + d]  + bhh[2*HID + d];
    const float bi3 = bih[3*HID + d]  + bhh[3*HID + d];
    const float wi0 = Wih[d], wi1 = Wih[HID + d], wi2 = Wih[2*HID + d], wi3 = Wih[3*HID + d];

#pragma unroll
    for (int r = 0; r < 4; ++r) {
        const int b = bbase + ty * 4 + r;
        float g0 = acc[r][0] + bi0;
        float g1 = acc[r][1] + bi1;
        float g2 = acc[r][2] + bi2;
        float g3 = acc[r][3] + bi3;
        if (mode == 0) {
            const float xv = x[b * TSEQ + t];
            g0 = __builtin_fmaf(xv, wi0, g0);
            g1 = __builtin_fmaf(xv, wi1, g1);
            g2 = __builtin_fmaf(xv, wi2, g2);
            g3 = __builtin_fmaf(xv, wi3, g3);
            const float cold = c[b * HID + d];
            const float cn = sigf(g1) * cold + sigf(g0) * tanhf(g2);
            const float hn = sigf(g3) * tanhf(cn);
            c[b * HID + d]    = cn;
            hout[b * HID + d] = hn;
        } else {
            dbase[b * G4 + d]           = g0;
            dbase[b * G4 + HID + d]     = g1;
            dbase[b * G4 + 2*HID + d]   = g2;
            dbase[b * G4 + 3*HID + d]   = g3;
        }
    }
}

// Autoregressive decoder: hidden/cell frozen, dec_base precomputed.
// One block per batch row; 42 sequential in-kernel steps.
__global__ __launch_bounds__(256) void lstm_dec(
    const float* __restrict__ hidden,  // [B,H]
    const float* __restrict__ dbase,   // [B,4H]
    const float* __restrict__ cell,    // [B,H]
    const float* __restrict__ Wih,     // [4H]
    const float* __restrict__ Wout,    // [H]
    const float* __restrict__ bout,    // [1]
    float* __restrict__ out)           // [B, DECSTEPS]
{
    const int b   = blockIdx.x;
    const int tid = threadIdx.x;
    __shared__ float red[8];

    const int dA = tid, dB = tid + 256;
    const float woA = Wout[dA], woB = Wout[dB];
    float hA = hidden[b * HID + dA], hB = hidden[b * HID + dB];
    const float cA = cell[b * HID + dA], cB = cell[b * HID + dB];
    const float biA = dbase[b * G4 + dA],          biB = dbase[b * G4 + dB];
    const float bfA = dbase[b * G4 + HID + dA],    bfB = dbase[b * G4 + HID + dB];
    const float bgA = dbase[b * G4 + 2*HID + dA],  bgB = dbase[b * G4 + 2*HID + dB];
    const float boA = dbase[b * G4 + 3*HID + dA],  boB = dbase[b * G4 + 3*HID + dB];
    const float wiA = Wih[dA],          wiB = Wih[dB];
    const float wfA = Wih[HID + dA],    wfB = Wih[HID + dB];
    const float wgA = Wih[2*HID + dA],  wgB = Wih[2*HID + dB];
    const float wxA = Wih[3*HID + dA],  wxB = Wih[3*HID + dB];
    const float bo  = bout[0];

    for (int s = 0; s < DECSTEPS; ++s) {
        // out = h . Wout + bout
        float p = hA * woA + hB * woB;
#pragma unroll
        for (int m = 1; m < 64; m <<= 1) p += __shfl_xor(p, m, 64);
        if ((tid & 63) == 0) red[tid >> 6] = p;
        __syncthreads();
        const float ov = red[0] + red[1] + red[2] + red[3] + bo;
        if (tid == 0) out[b * DECSTEPS + s] = ov;
        __syncthreads();  // protect red[] before next iteration

        // h_new from frozen cell + rank-1 gate update
        {
            const float gi = sigf(__builtin_fmaf(ov, wiA, biA));
            const float gf = sigf(__builtin_fmaf(ov, wfA, bfA));
            const float gg = tanhf(__builtin_fmaf(ov, wgA, bgA));
            const float go = sigf(__builtin_fmaf(ov, wxA, boA));
            const float cn = gf * cA + gi * gg;
            hA = go * tanhf(cn);
        }
        {
            const float gi = sigf(__builtin_fmaf(ov, wiB, biB));
            const float gf = sigf(__builtin_fmaf(ov, wfB, bfB));
            const float gg = tanhf(__builtin_fmaf(ov, wgB, bgB));
            const float go = sigf(__builtin_fmaf(ov, wxB, boB));
            const float cn = gf * cB + gi * gg;
            hB = go * tanhf(cn);
        }
    }
}

extern "C" void kernel_launch(void* const* d_in, const int* in_sizes, int n_in,
                              void* d_out, int out_size, void* d_ws, size_t ws_size,
                              hipStream_t stream) {
    const float* x    = (const float*)d_in[0];  // [B,T,1]
    const float* Wih  = (const float*)d_in[1];  // [4H,1]
    const float* Whh  = (const float*)d_in[2];  // [4H,H]
    const float* bih  = (const float*)d_in[3];
    const float* bhh  = (const float*)d_in[4];
    const float* Wout = (const float*)d_in[5];  // [1,H]
    const float* bout = (const float*)d_in[6];
    float* out = (float*)d_out;

    float* ws    = (float*)d_ws;
    float* h0    = ws;                 // [B,H] 1 MB
    float* h1    = ws + 262144;        // [B,H] 1 MB
    float* c     = ws + 524288;        // [B,H] 1 MB
    float* dbase = ws + 786432;        // [B,4H] 4 MB

    // zero h0, h1, c (ws is poisoned 0xAA before every launch)
    hipMemsetAsync(d_ws, 0, 3u * 1024u * 1024u, stream);

    dim3 grid(BATCH / BT, HID / DT);   // 8 x 32 = 256 blocks
    dim3 blk(256);

    for (int t = 0; t < TSEQ; ++t) {
        const float* hin = (t & 1) ? h1 : h0;
        float*       hto = (t & 1) ? h0 : h1;
        lstm_gemm<<<grid, blk, 0, stream>>>(hin, Whh, Wih, bih, bhh, x, t, 0, hto, c, nullptr);
    }
    // after t=255 (odd), final hidden lives in h0
    lstm_gemm<<<grid, blk, 0, stream>>>(h0, Whh, Wih, bih, bhh, x, 0, 1, nullptr, c, dbase);
    lstm_dec<<<dim3(BATCH), blk, 0, stream>>>(h0, dbase, c, Wih, Wout, bout, out);
}

// Round 4
// 2912.107 us; speedup vs baseline: 2.8604x; 2.8604x over previous
//
#include <hip/hip_runtime.h>
#include <math.h>

#define BATCH 512
#define TSEQ  256
#define HID   512
#define G4    2048
#define DECSTEPS 42

typedef __attribute__((ext_vector_type(8))) short short8v;
typedef __attribute__((ext_vector_type(16))) float f32x16;
typedef unsigned short u16;

__device__ __forceinline__ float sigf(float x){ return 1.0f/(1.0f+expf(-x)); }
__device__ __forceinline__ float bf2f(u16 u){ unsigned v = ((unsigned)u)<<16; return __builtin_bit_cast(float, v); }
__device__ __forceinline__ u16 f2bf(float f){
    unsigned u = __builtin_bit_cast(unsigned, f);
    u += 0x7fffu + ((u>>16)&1u);           // round-to-nearest-even
    return (u16)(u>>16);
}

// Split Whh fp32 -> bf16 hi/lo planes (hi = rn(x), lo = rn(x - hi))
__global__ __launch_bounds__(256) void split_whh(const float* __restrict__ W,
                                                 u16* __restrict__ hi, u16* __restrict__ lo){
    int i = (blockIdx.x*256 + threadIdx.x)*4;
    float4 v = *(const float4*)(W+i);
    u16 h0=f2bf(v.x), h1=f2bf(v.y), h2=f2bf(v.z), h3=f2bf(v.w);
    ushort4 hv = make_ushort4(h0,h1,h2,h3);
    ushort4 lv = make_ushort4(f2bf(v.x-bf2f(h0)), f2bf(v.y-bf2f(h1)),
                              f2bf(v.z-bf2f(h2)), f2bf(v.w-bf2f(h3)));
    *(ushort4*)(hi+i)=hv; *(ushort4*)(lo+i)=lv;
}

// One LSTM step via split-bf16 MFMA.
// mode 0: gates = h@Whh^T + x_t*Wih + b -> update c, write h (as hi/lo planes)
// mode 1: dbase = h@Whh^T + b (raw pre-activations)
__global__ __launch_bounds__(256) void lstm_step(
    const u16* __restrict__ hhi, const u16* __restrict__ hlo,   // [512][512]
    const u16* __restrict__ Whi, const u16* __restrict__ Wlo,   // [2048][512]
    const float* __restrict__ bih, const float* __restrict__ bhh,
    const float* __restrict__ Wih, const float* __restrict__ x,
    int t, int mode,
    u16* __restrict__ hohi, u16* __restrict__ holo,
    float* __restrict__ c, float* __restrict__ dbase)
{
    const int tid  = threadIdx.x;
    const int lane = tid & 63;
    const int wave = tid >> 6;
    const int wr = wave >> 1, wc = wave & 1;

    // XCD-aware remap: xcd g owns d-tiles [4g,4g+4) x all batch tiles (Whh slice L2-resident)
    int lin = (int)blockIdx.x + 8*(int)blockIdx.y;
    int xcd = lin & 7, s = lin >> 3;
    int by = xcd*4 + (s & 3);
    int bx = s >> 2;
    const int b0 = bx*64, d0 = by*16;

    __shared__ __align__(16) char smem[32768];
    short* Ahi = (short*)smem;              // [64][64] bf16, XOR-swizzled rows
    short* Alo = (short*)(smem + 8192);
    short* Bhi = (short*)(smem + 16384);
    short* Blo = (short*)(smem + 24576);
    float* Cls = (float*)smem;              // [64][64] f32 (reuses A region post-loop)

    // ---- staging mapping: thread -> (row, two 16B chunks) ----
    const int srow = tid >> 2;              // 0..63 (A: batch row / B: col index)
    const int scb  = (tid & 3) * 32;        // byte offset of first chunk within 128B row
    const int arow = b0 + srow;
    const int wrow = (srow >> 4)*HID + d0 + (srow & 15);  // col -> Whh row (g*512 + d)
    const u16* pAh = hhi + (size_t)arow*HID + (tid&3)*16;
    const u16* pAl = hlo + (size_t)arow*HID + (tid&3)*16;
    const u16* pBh = Whi + (size_t)wrow*HID + (tid&3)*16;
    const u16* pBl = Wlo + (size_t)wrow*HID + (tid&3)*16;
    const int swr = (srow & 7) << 4;
    const int wo0 = srow*128 + (scb ^ swr);
    const int wo1 = srow*128 + ((scb+16) ^ swr);

    // ---- MFMA fragment read addressing (32x32x16: row=lane&31, k=(lane>>5)*8+e) ----
    const int la   = lane & 31;
    const int hi16 = (lane >> 5) * 16;
    const int ra = wr*32 + la;              // A row (batch)
    const int rb = wc*32 + la;              // B col
    const int sa = (ra & 7) << 4;
    const int sb = (rb & 7) << 4;
    char* fAh = (char*)Ahi + ra*128;
    char* fAl = (char*)Alo + ra*128;
    char* fBh = (char*)Bhi + rb*128;
    char* fBl = (char*)Blo + rb*128;

    f32x16 acc0 = {}, acc1 = {}, acc2 = {};   // 3 chains: hi*hi, hi*lo, lo*hi

    uint4 r0,r1,r2,r3,r4,r5,r6,r7;
    // prologue: chunk 0 -> LDS
    r0 = *(const uint4*)(pAh);   r1 = *(const uint4*)(pAh+8);
    r2 = *(const uint4*)(pAl);   r3 = *(const uint4*)(pAl+8);
    r4 = *(const uint4*)(pBh);   r5 = *(const uint4*)(pBh+8);
    r6 = *(const uint4*)(pBl);   r7 = *(const uint4*)(pBl+8);
    *(uint4*)((char*)Ahi+wo0)=r0; *(uint4*)((char*)Ahi+wo1)=r1;
    *(uint4*)((char*)Alo+wo0)=r2; *(uint4*)((char*)Alo+wo1)=r3;
    *(uint4*)((char*)Bhi+wo0)=r4; *(uint4*)((char*)Bhi+wo1)=r5;
    *(uint4*)((char*)Blo+wo0)=r6; *(uint4*)((char*)Blo+wo1)=r7;

    for (int kc = 0; kc < 8; ++kc){
        __syncthreads();                    // LDS writes visible
        if (kc < 7){                        // prefetch next chunk into regs (overlaps MFMA)
            const int ko = (kc+1)*64;
            r0 = *(const uint4*)(pAh+ko); r1 = *(const uint4*)(pAh+ko+8);
            r2 = *(const uint4*)(pAl+ko); r3 = *(const uint4*)(pAl+ko+8);
            r4 = *(const uint4*)(pBh+ko); r5 = *(const uint4*)(pBh+ko+8);
            r6 = *(const uint4*)(pBl+ko); r7 = *(const uint4*)(pBl+ko+8);
        }
#pragma unroll
        for (int kk = 0; kk < 4; ++kk){
            const int off = kk*32 + hi16;
            short8v ah = *(short8v*)(fAh + (off ^ sa));
            short8v al = *(short8v*)(fAl + (off ^ sa));
            short8v bh = *(short8v*)(fBh + (off ^ sb));
            short8v bl = *(short8v*)(fBl + (off ^ sb));
            acc0 = __builtin_amdgcn_mfma_f32_32x32x16_bf16(ah, bh, acc0, 0,0,0);
            acc1 = __builtin_amdgcn_mfma_f32_32x32x16_bf16(ah, bl, acc1, 0,0,0);
            acc2 = __builtin_amdgcn_mfma_f32_32x32x16_bf16(al, bh, acc2, 0,0,0);
        }
        __syncthreads();                    // all frag reads done
        if (kc < 7){
            *(uint4*)((char*)Ahi+wo0)=r0; *(uint4*)((char*)Ahi+wo1)=r1;
            *(uint4*)((char*)Alo+wo0)=r2; *(uint4*)((char*)Alo+wo1)=r3;
            *(uint4*)((char*)Bhi+wo0)=r4; *(uint4*)((char*)Bhi+wo1)=r5;
            *(uint4*)((char*)Blo+wo0)=r6; *(uint4*)((char*)Blo+wo1)=r7;
        }
    }

    // ---- C quadrants -> LDS (fp32) ----
    f32x16 accs;
#pragma unroll
    for (int r = 0; r < 16; ++r) accs[r] = acc0[r] + acc1[r] + acc2[r];
#pragma unroll
    for (int r = 0; r < 16; ++r){
        const int crow = (r & 3) + 8*(r >> 2) + 4*(lane >> 5);   // measured C/D layout (m74/m101)
        Cls[(wr*32 + crow)*64 + wc*32 + la] = accs[r];
    }
    __syncthreads();

    // ---- cell epilogue: 4 (b,d) cells per thread ----
    const int dloc = tid & 15;
    const int bgrp = tid >> 4;
    const int d = d0 + dloc;
    const float bi0 = bih[d]         + bhh[d];
    const float bi1 = bih[HID+d]     + bhh[HID+d];
    const float bi2 = bih[2*HID+d]   + bhh[2*HID+d];
    const float bi3 = bih[3*HID+d]   + bhh[3*HID+d];
    if (mode == 0){
        const float wi0 = Wih[d], wi1 = Wih[HID+d], wi2 = Wih[2*HID+d], wi3 = Wih[3*HID+d];
#pragma unroll
        for (int i = 0; i < 4; ++i){
            const int bl = bgrp*4 + i;
            const int b  = b0 + bl;
            const float xv = x[b*TSEQ + t];
            const float g0 = Cls[bl*64 + dloc]      + bi0 + xv*wi0;
            const float g1 = Cls[bl*64 + 16 + dloc] + bi1 + xv*wi1;
            const float g2 = Cls[bl*64 + 32 + dloc] + bi2 + xv*wi2;
            const float g3 = Cls[bl*64 + 48 + dloc] + bi3 + xv*wi3;
            const float cold = c[b*HID + d];
            const float cn = sigf(g1)*cold + sigf(g0)*tanhf(g2);
            const float hn = sigf(g3)*tanhf(cn);
            c[b*HID + d] = cn;
            const u16 hh = f2bf(hn);
            hohi[b*HID + d] = hh;
            holo[b*HID + d] = f2bf(hn - bf2f(hh));
        }
    } else {
#pragma unroll
        for (int i = 0; i < 4; ++i){
            const int bl = bgrp*4 + i;
            const int b  = b0 + bl;
            dbase[b*G4 + d]         = Cls[bl*64 + dloc]      + bi0;
            dbase[b*G4 + HID + d]   = Cls[bl*64 + 16 + dloc] + bi1;
            dbase[b*G4 + 2*HID + d] = Cls[bl*64 + 32 + dloc] + bi2;
            dbase[b*G4 + 3*HID + d] = Cls[bl*64 + 48 + dloc] + bi3;
        }
    }
}

// Autoregressive decoder: hidden/cell frozen, dec_base precomputed. One block per batch row.
__global__ __launch_bounds__(256) void lstm_dec(
    const u16* __restrict__ hhi, const u16* __restrict__ hlo,
    const float* __restrict__ dbase, const float* __restrict__ cell,
    const float* __restrict__ Wih, const float* __restrict__ Wout,
    const float* __restrict__ bout, float* __restrict__ out)
{
    const int b   = blockIdx.x;
    const int tid = threadIdx.x;
    __shared__ float red[8];

    const int dA = tid, dB = tid + 256;
    const float woA = Wout[dA], woB = Wout[dB];
    float hA = bf2f(hhi[b*HID + dA]) + bf2f(hlo[b*HID + dA]);
    float hB = bf2f(hhi[b*HID + dB]) + bf2f(hlo[b*HID + dB]);
    const float cA = cell[b*HID + dA], cB = cell[b*HID + dB];
    const float biA = dbase[b*G4 + dA],          biB = dbase[b*G4 + dB];
    const float bfA = dbase[b*G4 + HID + dA],    bfB = dbase[b*G4 + HID + dB];
    const float bgA = dbase[b*G4 + 2*HID + dA],  bgB = dbase[b*G4 + 2*HID + dB];
    const float boA = dbase[b*G4 + 3*HID + dA],  boB = dbase[b*G4 + 3*HID + dB];
    const float wiA = Wih[dA],          wiB = Wih[dB];
    const float wfA = Wih[HID + dA],    wfB = Wih[HID + dB];
    const float wgA = Wih[2*HID + dA],  wgB = Wih[2*HID + dB];
    const float wxA = Wih[3*HID + dA],  wxB = Wih[3*HID + dB];
    const float bo  = bout[0];

    for (int s = 0; s < DECSTEPS; ++s) {
        float p = hA * woA + hB * woB;
#pragma unroll
        for (int m = 1; m < 64; m <<= 1) p += __shfl_xor(p, m, 64);
        if ((tid & 63) == 0) red[tid >> 6] = p;
        __syncthreads();
        const float ov = red[0] + red[1] + red[2] + red[3] + bo;
        if (tid == 0) out[b * DECSTEPS + s] = ov;
        __syncthreads();

        {
            const float gi = sigf(__builtin_fmaf(ov, wiA, biA));
            const float gf = sigf(__builtin_fmaf(ov, wfA, bfA));
            const float gg = tanhf(__builtin_fmaf(ov, wgA, bgA));
            const float go = sigf(__builtin_fmaf(ov, wxA, boA));
            hA = go * tanhf(gf * cA + gi * gg);
        }
        {
            const float gi = sigf(__builtin_fmaf(ov, wiB, biB));
            const float gf = sigf(__builtin_fmaf(ov, wfB, bfB));
            const float gg = tanhf(__builtin_fmaf(ov, wgB, bgB));
            const float go = sigf(__builtin_fmaf(ov, wxB, boB));
            hB = go * tanhf(gf * cB + gi * gg);
        }
    }
}

extern "C" void kernel_launch(void* const* d_in, const int* in_sizes, int n_in,
                              void* d_out, int out_size, void* d_ws, size_t ws_size,
                              hipStream_t stream) {
    const float* x    = (const float*)d_in[0];
    const float* Wih  = (const float*)d_in[1];
    const float* Whh  = (const float*)d_in[2];
    const float* bih  = (const float*)d_in[3];
    const float* bhh  = (const float*)d_in[4];
    const float* Wout = (const float*)d_in[5];
    const float* bout = (const float*)d_in[6];
    float* out = (float*)d_out;

    char* ws = (char*)d_ws;
    float* c     = (float*)(ws);                       // 1 MB
    float* dbase = (float*)(ws + (1u<<20));            // 4 MB
    u16*   Whi   = (u16*)  (ws + 5u*(1u<<20));         // 2 MB
    u16*   Wlo   = (u16*)  (ws + 7u*(1u<<20));         // 2 MB
    u16*   h0hi  = (u16*)  (ws + 9u*(1u<<20));         // 512 KB
    u16*   h0lo  = (u16*)  (ws + 9u*(1u<<20) + (1u<<19));
    u16*   h1hi  = (u16*)  (ws + 10u*(1u<<20));
    u16*   h1lo  = (u16*)  (ws + 10u*(1u<<20) + (1u<<19));

    hipMemsetAsync(c, 0, (1u<<20), stream);
    hipMemsetAsync(ws + 9u*(1u<<20), 0, (2u<<20), stream);
    split_whh<<<dim3(1024), dim3(256), 0, stream>>>(Whh, Whi, Wlo);

    dim3 grid(8,32), blk(256);
    for (int t = 0; t < TSEQ; ++t){
        const u16 *ihi, *ilo; u16 *ohi, *olo;
        if (t & 1){ ihi=h1hi; ilo=h1lo; ohi=h0hi; olo=h0lo; }
        else      { ihi=h0hi; ilo=h0lo; ohi=h1hi; olo=h1lo; }
        lstm_step<<<grid, blk, 0, stream>>>(ihi, ilo, Whi, Wlo, bih, bhh, Wih, x,
                                            t, 0, ohi, olo, c, nullptr);
    }
    // final hidden is in buf0 (T=256 even). Build decoder base, then decode.
    lstm_step<<<grid, blk, 0, stream>>>(h0hi, h0lo, Whi, Wlo, bih, bhh, Wih, x,
                                        0, 1, nullptr, nullptr, c, dbase);
    lstm_dec<<<dim3(BATCH), blk, 0, stream>>>(h0hi, h0lo, dbase, c, Wih, Wout, bout, out);
}

// Round 5
// 2735.340 us; speedup vs baseline: 3.0453x; 1.0646x over previous
//
#include <hip/hip_runtime.h>
#include <math.h>

#define BATCH 512
#define TSEQ  256
#define HID   512
#define G4    2048
#define DECSTEPS 42

typedef __attribute__((ext_vector_type(8))) short short8v;
typedef __attribute__((ext_vector_type(16))) float f32x16;
typedef unsigned short u16;

__device__ __forceinline__ float sigf(float x){ return 1.0f/(1.0f+expf(-x)); }
__device__ __forceinline__ float bf2f(u16 u){ unsigned v = ((unsigned)u)<<16; return __builtin_bit_cast(float, v); }
__device__ __forceinline__ u16 f2bf(float f){
    unsigned u = __builtin_bit_cast(unsigned, f);
    u += 0x7fffu + ((u>>16)&1u);           // round-to-nearest-even
    return (u16)(u>>16);
}

// Split Whh fp32 -> bf16 hi/lo planes (hi = rn(x), lo = rn(x - hi))
__global__ __launch_bounds__(256) void split_whh(const float* __restrict__ W,
                                                 u16* __restrict__ hi, u16* __restrict__ lo){
    int i = (blockIdx.x*256 + threadIdx.x)*4;
    float4 v = *(const float4*)(W+i);
    u16 h0=f2bf(v.x), h1=f2bf(v.y), h2=f2bf(v.z), h3=f2bf(v.w);
    ushort4 hv = make_ushort4(h0,h1,h2,h3);
    ushort4 lv = make_ushort4(f2bf(v.x-bf2f(h0)), f2bf(v.y-bf2f(h1)),
                              f2bf(v.z-bf2f(h2)), f2bf(v.w-bf2f(h3)));
    *(ushort4*)(hi+i)=hv; *(ushort4*)(lo+i)=lv;
}

// One LSTM step via split-bf16 MFMA. 8 waves: (row-quad, col-quad) x K-half.
// mode 0: gates = h@Whh^T + x_t*Wih + b -> update c, write h (hi/lo planes)
// mode 1: dbase = h@Whh^T + b (raw pre-activations)
__global__ __launch_bounds__(512, 2) void lstm_step(
    const u16* __restrict__ hhi, const u16* __restrict__ hlo,   // [512][512]
    const u16* __restrict__ Whi, const u16* __restrict__ Wlo,   // [2048][512]
    const float* __restrict__ bih, const float* __restrict__ bhh,
    const float* __restrict__ Wih, const float* __restrict__ x,
    int t, int mode,
    u16* __restrict__ hohi, u16* __restrict__ holo,
    float* __restrict__ c, float* __restrict__ dbase)
{
    const int tid  = threadIdx.x;
    const int lane = tid & 63;
    const int wave = tid >> 6;          // 0..7
    const int kh = wave >> 2;           // K-half (0: k<256, 1: k>=256)
    const int rq = (wave >> 1) & 1;     // row quadrant (batch)
    const int cq = wave & 1;            // col quadrant

    // XCD-aware remap: xcd g owns d-tiles [4g,4g+4) x all batch tiles
    int lin = (int)blockIdx.x + 8*(int)blockIdx.y;
    int xcd = lin & 7, s = lin >> 3;
    int by = xcd*4 + (s & 3);
    int bx = s >> 2;
    const int b0 = bx*64, d0 = by*16;

    // LDS: group g at [g*32768]: Ahi(8K) Alo(8K) Bhi(8K) Blo(8K). 64 KB total.
    // Cpart[2][64][64] f32 aliases it post-loop.
    __shared__ __align__(16) char smem[65536];

    // ---- staging: threads 0-255 -> group 0 (k 0..255), 256-511 -> group 1 ----
    const int tl   = tid & 255;
    const int g    = tid >> 8;
    const int srow = tl >> 2;               // 0..63 (A: batch row / B: col)
    const int scb  = (tl & 3) * 32;         // byte offset of first 16B chunk
    const int arow = b0 + srow;
    const int wrow = (srow >> 4)*HID + d0 + (srow & 15);  // col -> Whh row
    const int kb   = g*256 + (tl & 3)*16;   // element offset within K
    const u16* pAh = hhi + (size_t)arow*HID + kb;
    const u16* pAl = hlo + (size_t)arow*HID + kb;
    const u16* pBh = Whi + (size_t)wrow*HID + kb;
    const u16* pBl = Wlo + (size_t)wrow*HID + kb;
    char* sg = smem + g*32768;
    const int swr = (srow & 7) << 4;        // XOR swizzle (row&7)<<4
    const int wo0 = srow*128 + (scb ^ swr);
    const int wo1 = srow*128 + ((scb+16) ^ swr);

    // ---- MFMA fragment addressing (32x32x16: row=lane&31, k=(lane>>5)*8+e) ----
    const int la   = lane & 31;
    const int hi16 = (lane >> 5) * 16;
    const int ra = rq*32 + la;              // A row (batch)
    const int rb = cq*32 + la;              // B col
    const int sa = (ra & 7) << 4;
    const int sb = (rb & 7) << 4;
    char* mb  = smem + kh*32768;
    char* fAh = mb          + ra*128;
    char* fAl = mb + 8192   + ra*128;
    char* fBh = mb + 16384  + rb*128;
    char* fBl = mb + 24576  + rb*128;

    f32x16 acc0 = {}, acc1 = {}, acc2 = {};   // hi*hi, hi*lo, lo*hi

    uint4 r0,r1,r2,r3,r4,r5,r6,r7;
    // prologue: chunk 0 of this thread's group -> LDS
    r0 = *(const uint4*)(pAh);   r1 = *(const uint4*)(pAh+8);
    r2 = *(const uint4*)(pAl);   r3 = *(const uint4*)(pAl+8);
    r4 = *(const uint4*)(pBh);   r5 = *(const uint4*)(pBh+8);
    r6 = *(const uint4*)(pBl);   r7 = *(const uint4*)(pBl+8);
    *(uint4*)(sg+wo0)=r0;       *(uint4*)(sg+wo1)=r1;
    *(uint4*)(sg+8192+wo0)=r2;  *(uint4*)(sg+8192+wo1)=r3;
    *(uint4*)(sg+16384+wo0)=r4; *(uint4*)(sg+16384+wo1)=r5;
    *(uint4*)(sg+24576+wo0)=r6; *(uint4*)(sg+24576+wo1)=r7;

    for (int it = 0; it < 4; ++it){
        __syncthreads();                    // LDS writes visible
        if (it < 3){                        // prefetch next chunk into regs
            const int ko = (it+1)*64;
            r0 = *(const uint4*)(pAh+ko); r1 = *(const uint4*)(pAh+ko+8);
            r2 = *(const uint4*)(pAl+ko); r3 = *(const uint4*)(pAl+ko+8);
            r4 = *(const uint4*)(pBh+ko); r5 = *(const uint4*)(pBh+ko+8);
            r6 = *(const uint4*)(pBl+ko); r7 = *(const uint4*)(pBl+ko+8);
        }
#pragma unroll
        for (int kk = 0; kk < 4; ++kk){
            const int off = kk*32 + hi16;
            short8v ah = *(short8v*)(fAh + (off ^ sa));
            short8v al = *(short8v*)(fAl + (off ^ sa));
            short8v bh = *(short8v*)(fBh + (off ^ sb));
            short8v bl = *(short8v*)(fBl + (off ^ sb));
            acc0 = __builtin_amdgcn_mfma_f32_32x32x16_bf16(ah, bh, acc0, 0,0,0);
            acc1 = __builtin_amdgcn_mfma_f32_32x32x16_bf16(ah, bl, acc1, 0,0,0);
            acc2 = __builtin_amdgcn_mfma_f32_32x32x16_bf16(al, bh, acc2, 0,0,0);
        }
        __syncthreads();                    // all frag reads done
        if (it < 3){
            *(uint4*)(sg+wo0)=r0;       *(uint4*)(sg+wo1)=r1;
            *(uint4*)(sg+8192+wo0)=r2;  *(uint4*)(sg+8192+wo1)=r3;
            *(uint4*)(sg+16384+wo0)=r4; *(uint4*)(sg+16384+wo1)=r5;
            *(uint4*)(sg+24576+wo0)=r6; *(uint4*)(sg+24576+wo1)=r7;
        }
    }

    // ---- K-partials -> LDS f32 Cpart[kh][64][64] ----
    f32x16 accs;
#pragma unroll
    for (int r = 0; r < 16; ++r) accs[r] = acc0[r] + acc1[r] + acc2[r];
    float* Cp = (float*)smem;
#pragma unroll
    for (int r = 0; r < 16; ++r){
        const int crow = (r & 3) + 8*(r >> 2) + 4*(lane >> 5);   // C/D layout (m74/m101)
        Cp[kh*4096 + (rq*32 + crow)*64 + cq*32 + la] = accs[r];
    }
    __syncthreads();

    // ---- cell epilogue: 2 (b,d) cells per thread ----
    const int bl  = tid >> 3;               // 0..63
    const int b   = b0 + bl;
    const int dl0 = (tid & 7) * 2;
    if (mode == 0){
        const float xv = x[b*TSEQ + t];
#pragma unroll
        for (int j = 0; j < 2; ++j){
            const int dl = dl0 + j;
            const int d  = d0 + dl;
            const float g0 = Cp[bl*64 + dl]      + Cp[4096 + bl*64 + dl]      + bih[d]         + bhh[d]         + xv*Wih[d];
            const float g1 = Cp[bl*64 + 16 + dl] + Cp[4096 + bl*64 + 16 + dl] + bih[HID+d]     + bhh[HID+d]     + xv*Wih[HID+d];
            const float g2 = Cp[bl*64 + 32 + dl] + Cp[4096 + bl*64 + 32 + dl] + bih[2*HID+d]   + bhh[2*HID+d]   + xv*Wih[2*HID+d];
            const float g3 = Cp[bl*64 + 48 + dl] + Cp[4096 + bl*64 + 48 + dl] + bih[3*HID+d]   + bhh[3*HID+d]   + xv*Wih[3*HID+d];
            const float cold = c[b*HID + d];
            const float cn = sigf(g1)*cold + sigf(g0)*tanhf(g2);
            const float hn = sigf(g3)*tanhf(cn);
            c[b*HID + d] = cn;
            const u16 hh = f2bf(hn);
            hohi[b*HID + d] = hh;
            holo[b*HID + d] = f2bf(hn - bf2f(hh));
        }
    } else {
#pragma unroll
        for (int j = 0; j < 2; ++j){
            const int dl = dl0 + j;
            const int d  = d0 + dl;
            dbase[b*G4 + d]         = Cp[bl*64 + dl]      + Cp[4096 + bl*64 + dl]      + bih[d]       + bhh[d];
            dbase[b*G4 + HID + d]   = Cp[bl*64 + 16 + dl] + Cp[4096 + bl*64 + 16 + dl] + bih[HID+d]   + bhh[HID+d];
            dbase[b*G4 + 2*HID + d] = Cp[bl*64 + 32 + dl] + Cp[4096 + bl*64 + 32 + dl] + bih[2*HID+d] + bhh[2*HID+d];
            dbase[b*G4 + 3*HID + d] = Cp[bl*64 + 48 + dl] + Cp[4096 + bl*64 + 48 + dl] + bih[3*HID+d] + bhh[3*HID+d];
        }
    }
}

// Autoregressive decoder: hidden/cell frozen, dec_base precomputed. One block per batch row.
__global__ __launch_bounds__(256) void lstm_dec(
    const u16* __restrict__ hhi, const u16* __restrict__ hlo,
    const float* __restrict__ dbase, const float* __restrict__ cell,
    const float* __restrict__ Wih, const float* __restrict__ Wout,
    const float* __restrict__ bout, float* __restrict__ out)
{
    const int b   = blockIdx.x;
    const int tid = threadIdx.x;
    __shared__ float red[8];

    const int dA = tid, dB = tid + 256;
    const float woA = Wout[dA], woB = Wout[dB];
    float hA = bf2f(hhi[b*HID + dA]) + bf2f(hlo[b*HID + dA]);
    float hB = bf2f(hhi[b*HID + dB]) + bf2f(hlo[b*HID + dB]);
    const float cA = cell[b*HID + dA], cB = cell[b*HID + dB];
    const float biA = dbase[b*G4 + dA],          biB = dbase[b*G4 + dB];
    const float bfA = dbase[b*G4 + HID + dA],    bfB = dbase[b*G4 + HID + dB];
    const float bgA = dbase[b*G4 + 2*HID + dA],  bgB = dbase[b*G4 + 2*HID + dB];
    const float boA = dbase[b*G4 + 3*HID + dA],  boB = dbase[b*G4 + 3*HID + dB];
    const float wiA = Wih[dA],          wiB = Wih[dB];
    const float wfA = Wih[HID + dA],    wfB = Wih[HID + dB];
    const float wgA = Wih[2*HID + dA],  wgB = Wih[2*HID + dB];
    const float wxA = Wih[3*HID + dA],  wxB = Wih[3*HID + dB];
    const float bo  = bout[0];

    for (int s = 0; s < DECSTEPS; ++s) {
        float p = hA * woA + hB * woB;
#pragma unroll
        for (int m = 1; m < 64; m <<= 1) p += __shfl_xor(p, m, 64);
        if ((tid & 63) == 0) red[tid >> 6] = p;
        __syncthreads();
        const float ov = red[0] + red[1] + red[2] + red[3] + bo;
        if (tid == 0) out[b * DECSTEPS + s] = ov;
        __syncthreads();

        {
            const float gi = sigf(__builtin_fmaf(ov, wiA, biA));
            const float gf = sigf(__builtin_fmaf(ov, wfA, bfA));
            const float gg = tanhf(__builtin_fmaf(ov, wgA, bgA));
            const float go = sigf(__builtin_fmaf(ov, wxA, boA));
            hA = go * tanhf(gf * cA + gi * gg);
        }
        {
            const float gi = sigf(__builtin_fmaf(ov, wiB, biB));
            const float gf = sigf(__builtin_fmaf(ov, wfB, bfB));
            const float gg = tanhf(__builtin_fmaf(ov, wgB, bgB));
            const float go = sigf(__builtin_fmaf(ov, wxB, boB));
            hB = go * tanhf(gf * cB + gi * gg);
        }
    }
}

extern "C" void kernel_launch(void* const* d_in, const int* in_sizes, int n_in,
                              void* d_out, int out_size, void* d_ws, size_t ws_size,
                              hipStream_t stream) {
    const float* x    = (const float*)d_in[0];
    const float* Wih  = (const float*)d_in[1];
    const float* Whh  = (const float*)d_in[2];
    const float* bih  = (const float*)d_in[3];
    const float* bhh  = (const float*)d_in[4];
    const float* Wout = (const float*)d_in[5];
    const float* bout = (const float*)d_in[6];
    float* out = (float*)d_out;

    char* ws = (char*)d_ws;
    float* c     = (float*)(ws);                       // 1 MB
    float* dbase = (float*)(ws + (1u<<20));            // 4 MB
    u16*   Whi   = (u16*)  (ws + 5u*(1u<<20));         // 2 MB
    u16*   Wlo   = (u16*)  (ws + 7u*(1u<<20));         // 2 MB
    u16*   h0hi  = (u16*)  (ws + 9u*(1u<<20));         // 512 KB
    u16*   h0lo  = (u16*)  (ws + 9u*(1u<<20) + (1u<<19));
    u16*   h1hi  = (u16*)  (ws + 10u*(1u<<20));
    u16*   h1lo  = (u16*)  (ws + 10u*(1u<<20) + (1u<<19));

    hipMemsetAsync(c, 0, (1u<<20), stream);
    hipMemsetAsync(ws + 9u*(1u<<20), 0, (2u<<20), stream);
    split_whh<<<dim3(1024), dim3(256), 0, stream>>>(Whh, Whi, Wlo);

    dim3 grid(8,32), blk(512);
    for (int t = 0; t < TSEQ; ++t){
        const u16 *ihi, *ilo; u16 *ohi, *olo;
        if (t & 1){ ihi=h1hi; ilo=h1lo; ohi=h0hi; olo=h0lo; }
        else      { ihi=h0hi; ilo=h0lo; ohi=h1hi; olo=h1lo; }
        lstm_step<<<grid, blk, 0, stream>>>(ihi, ilo, Whi, Wlo, bih, bhh, Wih, x,
                                            t, 0, ohi, olo, c, nullptr);
    }
    // final hidden is in buf0 (T=256 even). Build decoder base, then decode.
    lstm_step<<<grid, blk, 0, stream>>>(h0hi, h0lo, Whi, Wlo, bih, bhh, Wih, x,
                                        0, 1, nullptr, nullptr, c, dbase);
    lstm_dec<<<dim3(BATCH), dim3(256), 0, stream>>>(h0hi, h0lo, dbase, c, Wih, Wout, bout, out);
}